// Round 1
// baseline (2311.501 us; speedup 1.0000x reference)
//
#include <hip/hip_runtime.h>
#include <math.h>

#define BB   8
#define DIMM 1024
#define TT   2048
#define CDD  128
#define KK   1024
#define QQ   8
#define MM   (BB*TT)   // 16384 tokens

// ---------------------------------------------------------------------------
// ||E_k||^2 for all Q*K codebook rows. One wave per row.
__global__ __launch_bounds__(64) void enorm_kernel(const float* __restrict__ E,
                                                   float* __restrict__ en) {
    int row = blockIdx.x;
    int lane = threadIdx.x;
    const float* e = E + (size_t)row * CDD;
    float v0 = e[lane], v1 = e[lane + 64];
    float s = v0 * v0 + v1 * v1;
    #pragma unroll
    for (int off = 32; off > 0; off >>= 1) s += __shfl_down(s, off);
    if (lane == 0) en[row] = s;
}

// ---------------------------------------------------------------------------
// h[m, c] = sum_d (emb[b,d,t] - acc[b,d,t]) * Wi[d,c] + bi[c]
// m = b*T + t. 64-token M-tile (within one batch), full N=128, K-chunks of 32.
__global__ __launch_bounds__(256) void proj_in_kernel(
    const float* __restrict__ emb, const float* __restrict__ acc,
    const float* __restrict__ Wi, const float* __restrict__ bi,
    float* __restrict__ h)
{
    __shared__ float As[32][64];    // [k][t]
    __shared__ float Ws[32][128];   // [k][c]
    const int tid = threadIdx.x;
    const int m0 = blockIdx.x * 64;
    const int b = m0 / TT, t0 = m0 % TT;
    const float* eb = emb + (size_t)b * DIMM * TT + t0;
    const float* ab = acc + (size_t)b * DIMM * TT + t0;
    const int tx = tid & 15, ty = tid >> 4;   // tx -> 4 tokens, ty -> 8 c

    float r[4][8];
    #pragma unroll
    for (int i = 0; i < 4; i++)
        #pragma unroll
        for (int j = 0; j < 8; j++) r[i][j] = 0.f;

    for (int d0 = 0; d0 < DIMM; d0 += 32) {
        #pragma unroll
        for (int i = 0; i < 2; i++) {           // A tile: 32x64
            int j = i * 256 + tid;
            int row = j >> 4, c = (j & 15) << 2;
            const float4 ev = *(const float4*)(eb + (size_t)(d0 + row) * TT + c);
            const float4 av = *(const float4*)(ab + (size_t)(d0 + row) * TT + c);
            float4 v; v.x = ev.x - av.x; v.y = ev.y - av.y;
                      v.z = ev.z - av.z; v.w = ev.w - av.w;
            *(float4*)&As[row][c] = v;
        }
        #pragma unroll
        for (int i = 0; i < 4; i++) {           // W tile: 32x128
            int j = i * 256 + tid;
            int row = j >> 5, c = (j & 31) << 2;
            *(float4*)&Ws[row][c] = *(const float4*)(Wi + (size_t)(d0 + row) * CDD + c);
        }
        __syncthreads();
        #pragma unroll
        for (int kk = 0; kk < 32; kk++) {
            float4 a4 = *(float4*)&As[kk][tx << 2];
            float4 w0 = *(float4*)&Ws[kk][ty << 3];
            float4 w1 = *(float4*)&Ws[kk][(ty << 3) + 4];
            float av[4] = {a4.x, a4.y, a4.z, a4.w};
            float wv[8] = {w0.x, w0.y, w0.z, w0.w, w1.x, w1.y, w1.z, w1.w};
            #pragma unroll
            for (int i = 0; i < 4; i++)
                #pragma unroll
                for (int j = 0; j < 8; j++)
                    r[i][j] = fmaf(av[i], wv[j], r[i][j]);
        }
        __syncthreads();
    }
    float bv[8];
    #pragma unroll
    for (int j = 0; j < 8; j++) bv[j] = bi[(ty << 3) + j];
    #pragma unroll
    for (int i = 0; i < 4; i++) {
        int m = m0 + (tx << 2) + i;
        float* hp = h + (size_t)m * CDD + (ty << 3);
        float4 o0, o1;
        o0.x = r[i][0] + bv[0]; o0.y = r[i][1] + bv[1];
        o0.z = r[i][2] + bv[2]; o0.w = r[i][3] + bv[3];
        o1.x = r[i][4] + bv[4]; o1.y = r[i][5] + bv[5];
        o1.z = r[i][6] + bv[6]; o1.w = r[i][7] + bv[7];
        *(float4*)(hp)     = o0;
        *(float4*)(hp + 4) = o1;
    }
}

// ---------------------------------------------------------------------------
// idx[m] = argmin_k ( en[k] - 2 * h[m,:] . E[k,:] )   (|h|^2 constant per m)
// 64-token tile per block; stream E in 64-code chunks through LDS.
__global__ __launch_bounds__(256) void argmin_kernel(
    const float* __restrict__ h, const float* __restrict__ E,
    const float* __restrict__ en, int* __restrict__ outidx)
{
    __shared__ float Hs[64][132];
    __shared__ float Es[64][132];
    __shared__ float redv[64][16];
    __shared__ int   redi[64][16];
    const int tid = threadIdx.x;
    const int m0 = blockIdx.x * 64;
    const int tx = tid & 15, ty = tid >> 4;  // tx -> codes (stride16), ty -> 4 tokens

    #pragma unroll
    for (int i = 0; i < 8; i++) {
        int j = i * 256 + tid;
        int row = j >> 5, c = (j & 31) << 2;
        *(float4*)&Hs[row][c] = *(const float4*)(h + (size_t)(m0 + row) * CDD + c);
    }

    float bestv[4]; int besti[4];
    #pragma unroll
    for (int i = 0; i < 4; i++) { bestv[i] = INFINITY; besti[i] = 0; }

    for (int k0 = 0; k0 < KK; k0 += 64) {
        __syncthreads();
        #pragma unroll
        for (int i = 0; i < 8; i++) {
            int j = i * 256 + tid;
            int row = j >> 5, c = (j & 31) << 2;
            *(float4*)&Es[row][c] = *(const float4*)(E + (size_t)(k0 + row) * CDD + c);
        }
        __syncthreads();
        float dot[4][4];
        #pragma unroll
        for (int i = 0; i < 4; i++)
            #pragma unroll
            for (int j = 0; j < 4; j++) dot[i][j] = 0.f;
        #pragma unroll 4
        for (int c = 0; c < CDD; c += 4) {
            float4 hv[4], ev[4];
            #pragma unroll
            for (int i = 0; i < 4; i++) hv[i] = *(float4*)&Hs[(ty << 2) + i][c];
            #pragma unroll
            for (int j = 0; j < 4; j++) ev[j] = *(float4*)&Es[tx + (j << 4)][c];
            #pragma unroll
            for (int i = 0; i < 4; i++)
                #pragma unroll
                for (int j = 0; j < 4; j++) {
                    dot[i][j] = fmaf(hv[i].x, ev[j].x, dot[i][j]);
                    dot[i][j] = fmaf(hv[i].y, ev[j].y, dot[i][j]);
                    dot[i][j] = fmaf(hv[i].z, ev[j].z, dot[i][j]);
                    dot[i][j] = fmaf(hv[i].w, ev[j].w, dot[i][j]);
                }
        }
        #pragma unroll
        for (int j = 0; j < 4; j++) {
            int k = k0 + tx + (j << 4);
            float nrm = en[k];
            #pragma unroll
            for (int i = 0; i < 4; i++) {
                float s = fmaf(-2.f, dot[i][j], nrm);
                if (s < bestv[i]) { bestv[i] = s; besti[i] = k; }  // ascending k => first-min kept
            }
        }
    }
    #pragma unroll
    for (int i = 0; i < 4; i++) {
        redv[(ty << 2) + i][tx] = bestv[i];
        redi[(ty << 2) + i][tx] = besti[i];
    }
    __syncthreads();
    if (tid < 64) {
        float bv = INFINITY; int bi = (1 << 30);
        #pragma unroll
        for (int x = 0; x < 16; x++) {
            float v = redv[tid][x]; int ii = redi[tid][x];
            if (v < bv || (v == bv && ii < bi)) { bv = v; bi = ii; }
        }
        outidx[m0 + tid] = bi;
    }
}

// ---------------------------------------------------------------------------
// acc[b, d, t] += sum_c E[idx[m], c] * Wo[c, d] + bo[d]
// 64 tokens x 64 d per block, K=CD=128 single pass.
__global__ __launch_bounds__(256) void decode_kernel(
    const int* __restrict__ idxp, const float* __restrict__ E,
    const float* __restrict__ Wo, const float* __restrict__ bo,
    float* __restrict__ acc)
{
    __shared__ float As[64][132];   // gathered codebook rows [token][c]
    __shared__ float Bs[128][68];   // Wo [c][d_sub]
    __shared__ int ids[64];
    const int tid = threadIdx.x;
    const int m0 = blockIdx.x * 64;
    const int d0 = blockIdx.y * 64;
    const int b = m0 / TT, t0 = m0 % TT;
    const int tx = tid & 15, ty = tid >> 4;  // tx -> tokens (stride16), ty -> 4 d

    if (tid < 64) ids[tid] = idxp[m0 + tid];
    __syncthreads();
    #pragma unroll
    for (int i = 0; i < 8; i++) {
        int j = i * 256 + tid;
        int row = j >> 5, c = (j & 31) << 2;
        *(float4*)&As[row][c] = *(const float4*)(E + (size_t)ids[row] * CDD + c);
    }
    #pragma unroll
    for (int i = 0; i < 8; i++) {
        int j = i * 256 + tid;
        int row = j >> 4, c = (j & 15) << 2;
        *(float4*)&Bs[row][c] = *(const float4*)(Wo + (size_t)row * DIMM + d0 + c);
    }
    __syncthreads();

    float dot[4][4];
    #pragma unroll
    for (int i = 0; i < 4; i++)
        #pragma unroll
        for (int j = 0; j < 4; j++) dot[i][j] = 0.f;

    #pragma unroll 4
    for (int c = 0; c < CDD; c += 4) {
        float4 av[4];
        #pragma unroll
        for (int i = 0; i < 4; i++) av[i] = *(float4*)&As[tx + (i << 4)][c];
        float4 b0 = *(float4*)&Bs[c + 0][ty << 2];
        float4 b1 = *(float4*)&Bs[c + 1][ty << 2];
        float4 b2 = *(float4*)&Bs[c + 2][ty << 2];
        float4 b3 = *(float4*)&Bs[c + 3][ty << 2];
        #pragma unroll
        for (int i = 0; i < 4; i++) {
            dot[i][0] = fmaf(av[i].x, b0.x, dot[i][0]);
            dot[i][1] = fmaf(av[i].x, b0.y, dot[i][1]);
            dot[i][2] = fmaf(av[i].x, b0.z, dot[i][2]);
            dot[i][3] = fmaf(av[i].x, b0.w, dot[i][3]);
            dot[i][0] = fmaf(av[i].y, b1.x, dot[i][0]);
            dot[i][1] = fmaf(av[i].y, b1.y, dot[i][1]);
            dot[i][2] = fmaf(av[i].y, b1.z, dot[i][2]);
            dot[i][3] = fmaf(av[i].y, b1.w, dot[i][3]);
            dot[i][0] = fmaf(av[i].z, b2.x, dot[i][0]);
            dot[i][1] = fmaf(av[i].z, b2.y, dot[i][1]);
            dot[i][2] = fmaf(av[i].z, b2.z, dot[i][2]);
            dot[i][3] = fmaf(av[i].z, b2.w, dot[i][3]);
            dot[i][0] = fmaf(av[i].w, b3.x, dot[i][0]);
            dot[i][1] = fmaf(av[i].w, b3.y, dot[i][1]);
            dot[i][2] = fmaf(av[i].w, b3.z, dot[i][2]);
            dot[i][3] = fmaf(av[i].w, b3.w, dot[i][3]);
        }
    }

    #pragma unroll
    for (int j = 0; j < 4; j++) {
        int d = d0 + (ty << 2) + j;
        float bj = bo[d];
        float* base = acc + (size_t)b * DIMM * TT + (size_t)d * TT + t0 + tx;
        #pragma unroll
        for (int i = 0; i < 4; i++) {
            base[i << 4] += dot[i][j] + bj;   // coalesced across tx (consecutive t)
        }
    }
}

// ---------------------------------------------------------------------------
extern "C" void kernel_launch(void* const* d_in, const int* in_sizes, int n_in,
                              void* d_out, int out_size, void* d_ws, size_t ws_size,
                              hipStream_t stream) {
    const float* emb   = (const float*)d_in[0];
    const float* W_in  = (const float*)d_in[1];
    const float* b_in  = (const float*)d_in[2];
    const float* W_out = (const float*)d_in[3];
    const float* b_out = (const float*)d_in[4];
    const float* embed = (const float*)d_in[5];
    float* acc = (float*)d_out;                             // quantized sum, also 'emb - acc' = residual

    float* h      = (float*)d_ws;                           // MM*CDD floats = 8 MB
    int*   idxbuf = (int*)((char*)d_ws + (size_t)MM * CDD * 4);
    float* en     = (float*)((char*)d_ws + (size_t)MM * CDD * 4 + (size_t)MM * 4);

    hipMemsetAsync(d_out, 0, (size_t)BB * DIMM * TT * sizeof(float), stream);
    enorm_kernel<<<QQ * KK, 64, 0, stream>>>(embed, en);

    for (int q = 0; q < QQ; q++) {
        proj_in_kernel<<<MM / 64, 256, 0, stream>>>(
            emb, acc, W_in + (size_t)q * DIMM * CDD, b_in + (size_t)q * CDD, h);
        argmin_kernel<<<MM / 64, 256, 0, stream>>>(
            h, embed + (size_t)q * KK * CDD, en + (size_t)q * KK, idxbuf);
        decode_kernel<<<dim3(MM / 64, DIMM / 64), 256, 0, stream>>>(
            idxbuf, embed + (size_t)q * KK * CDD, W_out + (size_t)q * CDD * DIMM,
            b_out + (size_t)q * DIMM, acc);
    }
}

// Round 2
// 1944.057 us; speedup vs baseline: 1.1890x; 1.1890x over previous
//
#include <hip/hip_runtime.h>
#include <math.h>

#define BB   8
#define DIMM 1024
#define TT   2048
#define CDD  128
#define KK   1024
#define QQ   8
#define MM   (BB*TT)   // 16384 tokens
#define TILE 32        // tokens per block in fused kernel

// ---------------------------------------------------------------------------
// ||E_k||^2 for all Q*K codebook rows. One wave per row.
__global__ __launch_bounds__(64) void enorm_kernel(const float* __restrict__ E,
                                                   float* __restrict__ en) {
    int row = blockIdx.x;
    int lane = threadIdx.x;
    const float* e = E + (size_t)row * CDD;
    float v0 = e[lane], v1 = e[lane + 64];
    float s = v0 * v0 + v1 * v1;
    #pragma unroll
    for (int off = 32; off > 0; off >>= 1) s += __shfl_down(s, off);
    if (lane == 0) en[row] = s;
}

// ---------------------------------------------------------------------------
// Fused: h = (emb-acc)^T . Wi + bi  (in LDS), then idx = argmin_k en[k]-2 h.E[k]
// 32 tokens per block, 512 blocks (2/CU), 256 threads.
__global__ __launch_bounds__(256) void fused_pa_kernel(
    const float* __restrict__ emb, const float* __restrict__ acc,
    const float* __restrict__ Wi, const float* __restrict__ bi,
    const float* __restrict__ E, const float* __restrict__ en,
    int* __restrict__ outidx)
{
    static __shared__ __align__(16) char smem[50688];
    float (*As)[32]   = (float(*)[32])smem;            // [d][t]  8 KB (phase 1)
    float (*Ws)[128]  = (float(*)[128])(smem + 8192);  // [d][c] 32 KB (phase 1)
    float (*Hs)[132]  = (float(*)[132])smem;           // [t][c] 16.9 KB (phase 2)
    float (*Es)[132]  = (float(*)[132])(smem + 16896); // [k][c] 33.8 KB (phase 2)
    float (*redv)[16] = (float(*)[16])smem;            // reduce scratch (end)
    int   (*redi)[16] = (int(*)[16])(smem + 2048);

    const int tid = threadIdx.x;
    const int m0 = blockIdx.x * TILE;
    const int b = m0 / TT, t0 = m0 % TT;
    const float* eb = emb + (size_t)b * DIMM * TT + t0;
    const float* ab = acc + (size_t)b * DIMM * TT + t0;

    // ---- phase 1: h[32 t][128 c], thread tile 4t x 4c ----
    const int tx = tid & 7;    // token group: t = tx*4 .. +3
    const int cy = tid >> 3;   // c group: c = cy*4 .. +3
    float r[4][4];
    #pragma unroll
    for (int i = 0; i < 4; i++)
        #pragma unroll
        for (int j = 0; j < 4; j++) r[i][j] = 0.f;

    for (int d0 = 0; d0 < DIMM; d0 += 64) {
        #pragma unroll
        for (int i = 0; i < 2; i++) {              // As: 64d x 32t
            int j = i * 256 + tid;
            int row = j >> 3, col = (j & 7) << 2;
            const float4 ev = *(const float4*)(eb + (size_t)(d0 + row) * TT + col);
            const float4 av = *(const float4*)(ab + (size_t)(d0 + row) * TT + col);
            float4 v; v.x = ev.x - av.x; v.y = ev.y - av.y;
                      v.z = ev.z - av.z; v.w = ev.w - av.w;
            *(float4*)&As[row][col] = v;
        }
        #pragma unroll
        for (int i = 0; i < 8; i++) {              // Ws: 64d x 128c
            int j = i * 256 + tid;
            int row = j >> 5, col = (j & 31) << 2;
            *(float4*)&Ws[row][col] = *(const float4*)(Wi + (size_t)(d0 + row) * CDD + col);
        }
        __syncthreads();
        #pragma unroll 4
        for (int kk = 0; kk < 64; kk++) {
            float4 a4 = *(float4*)&As[kk][tx << 2];
            float4 w4 = *(float4*)&Ws[kk][cy << 2];
            float av[4] = {a4.x, a4.y, a4.z, a4.w};
            float wv[4] = {w4.x, w4.y, w4.z, w4.w};
            #pragma unroll
            for (int i = 0; i < 4; i++)
                #pragma unroll
                for (int j = 0; j < 4; j++)
                    r[i][j] = fmaf(av[i], wv[j], r[i][j]);
        }
        __syncthreads();
    }

    // write h (+bias) into LDS (overlaps As/Ws, after sync above)
    {
        float bv[4];
        #pragma unroll
        for (int j = 0; j < 4; j++) bv[j] = bi[(cy << 2) + j];
        #pragma unroll
        for (int i = 0; i < 4; i++) {
            float4 o;
            o.x = r[i][0] + bv[0]; o.y = r[i][1] + bv[1];
            o.z = r[i][2] + bv[2]; o.w = r[i][3] + bv[3];
            *(float4*)&Hs[(tx << 2) + i][cy << 2] = o;
        }
    }
    __syncthreads();

    // ---- phase 2: argmin over 1024 codes, thread tile 2t x 4k ----
    const int ktx = tid & 15;   // code lane (stride 16)
    const int kty = tid >> 4;   // token pair: t = kty*2 .. +1
    float bestv[2]; int besti[2];
    bestv[0] = bestv[1] = INFINITY; besti[0] = besti[1] = 0;

    for (int k0 = 0; k0 < KK; k0 += 64) {
        #pragma unroll
        for (int i = 0; i < 8; i++) {              // Es: 64k x 128c
            int j = i * 256 + tid;
            int row = j >> 5, col = (j & 31) << 2;
            *(float4*)&Es[row][col] = *(const float4*)(E + (size_t)(k0 + row) * CDD + col);
        }
        __syncthreads();
        float dot[2][4];
        #pragma unroll
        for (int i = 0; i < 2; i++)
            #pragma unroll
            for (int j = 0; j < 4; j++) dot[i][j] = 0.f;
        #pragma unroll 4
        for (int c = 0; c < CDD; c += 4) {
            float4 hv[2], ev[4];
            #pragma unroll
            for (int i = 0; i < 2; i++) hv[i] = *(float4*)&Hs[(kty << 1) + i][c];
            #pragma unroll
            for (int j = 0; j < 4; j++) ev[j] = *(float4*)&Es[ktx + (j << 4)][c];
            #pragma unroll
            for (int i = 0; i < 2; i++)
                #pragma unroll
                for (int j = 0; j < 4; j++) {
                    dot[i][j] = fmaf(hv[i].x, ev[j].x, dot[i][j]);
                    dot[i][j] = fmaf(hv[i].y, ev[j].y, dot[i][j]);
                    dot[i][j] = fmaf(hv[i].z, ev[j].z, dot[i][j]);
                    dot[i][j] = fmaf(hv[i].w, ev[j].w, dot[i][j]);
                }
        }
        #pragma unroll
        for (int j = 0; j < 4; j++) {
            int k = k0 + ktx + (j << 4);
            float nrm = en[k];
            #pragma unroll
            for (int i = 0; i < 2; i++) {
                float s = fmaf(-2.f, dot[i][j], nrm);
                if (s < bestv[i]) { bestv[i] = s; besti[i] = k; } // ascending k keeps first-min
            }
        }
        __syncthreads();   // before next chunk overwrites Es
    }

    // ---- cross-thread reduce (16 partial mins per token) ----
    #pragma unroll
    for (int i = 0; i < 2; i++) {
        redv[(kty << 1) + i][ktx] = bestv[i];
        redi[(kty << 1) + i][ktx] = besti[i];
    }
    __syncthreads();
    if (tid < TILE) {
        float bv = INFINITY; int bi2 = (1 << 30);
        #pragma unroll
        for (int x = 0; x < 16; x++) {
            float v = redv[tid][x]; int ii = redi[tid][x];
            if (v < bv || (v == bv && ii < bi2)) { bv = v; bi2 = ii; }
        }
        outidx[m0 + tid] = bi2;
    }
}

// ---------------------------------------------------------------------------
// acc[b, d, t] += sum_c E[idx[m], c] * Wo[c, d] + bo[d]
// 64 tokens x 64 d per block, K=CD=128 single pass.
__global__ __launch_bounds__(256) void decode_kernel(
    const int* __restrict__ idxp, const float* __restrict__ E,
    const float* __restrict__ Wo, const float* __restrict__ bo,
    float* __restrict__ acc)
{
    __shared__ float As[64][132];   // gathered codebook rows [token][c]
    __shared__ float Bs[128][68];   // Wo [c][d_sub]
    __shared__ int ids[64];
    const int tid = threadIdx.x;
    const int m0 = blockIdx.x * 64;
    const int d0 = blockIdx.y * 64;
    const int b = m0 / TT, t0 = m0 % TT;
    const int tx = tid & 15, ty = tid >> 4;  // tx -> tokens (stride16), ty -> 4 d

    if (tid < 64) ids[tid] = idxp[m0 + tid];
    __syncthreads();
    #pragma unroll
    for (int i = 0; i < 8; i++) {
        int j = i * 256 + tid;
        int row = j >> 5, c = (j & 31) << 2;
        *(float4*)&As[row][c] = *(const float4*)(E + (size_t)ids[row] * CDD + c);
    }
    #pragma unroll
    for (int i = 0; i < 8; i++) {
        int j = i * 256 + tid;
        int row = j >> 4, c = (j & 15) << 2;
        *(float4*)&Bs[row][c] = *(const float4*)(Wo + (size_t)row * DIMM + d0 + c);
    }
    __syncthreads();

    float dot[4][4];
    #pragma unroll
    for (int i = 0; i < 4; i++)
        #pragma unroll
        for (int j = 0; j < 4; j++) dot[i][j] = 0.f;

    #pragma unroll 4
    for (int c = 0; c < CDD; c += 4) {
        float4 av[4];
        #pragma unroll
        for (int i = 0; i < 4; i++) av[i] = *(float4*)&As[tx + (i << 4)][c];
        float4 b0 = *(float4*)&Bs[c + 0][ty << 2];
        float4 b1 = *(float4*)&Bs[c + 1][ty << 2];
        float4 b2 = *(float4*)&Bs[c + 2][ty << 2];
        float4 b3 = *(float4*)&Bs[c + 3][ty << 2];
        #pragma unroll
        for (int i = 0; i < 4; i++) {
            dot[i][0] = fmaf(av[i].x, b0.x, dot[i][0]);
            dot[i][1] = fmaf(av[i].x, b0.y, dot[i][1]);
            dot[i][2] = fmaf(av[i].x, b0.z, dot[i][2]);
            dot[i][3] = fmaf(av[i].x, b0.w, dot[i][3]);
            dot[i][0] = fmaf(av[i].y, b1.x, dot[i][0]);
            dot[i][1] = fmaf(av[i].y, b1.y, dot[i][1]);
            dot[i][2] = fmaf(av[i].y, b1.z, dot[i][2]);
            dot[i][3] = fmaf(av[i].y, b1.w, dot[i][3]);
            dot[i][0] = fmaf(av[i].z, b2.x, dot[i][0]);
            dot[i][1] = fmaf(av[i].z, b2.y, dot[i][1]);
            dot[i][2] = fmaf(av[i].z, b2.z, dot[i][2]);
            dot[i][3] = fmaf(av[i].z, b2.w, dot[i][3]);
            dot[i][0] = fmaf(av[i].w, b3.x, dot[i][0]);
            dot[i][1] = fmaf(av[i].w, b3.y, dot[i][1]);
            dot[i][2] = fmaf(av[i].w, b3.z, dot[i][2]);
            dot[i][3] = fmaf(av[i].w, b3.w, dot[i][3]);
        }
    }

    #pragma unroll
    for (int j = 0; j < 4; j++) {
        int d = d0 + (ty << 2) + j;
        float bj = bo[d];
        float* base = acc + (size_t)b * DIMM * TT + (size_t)d * TT + t0 + tx;
        #pragma unroll
        for (int i = 0; i < 4; i++) {
            base[i << 4] += dot[i][j] + bj;   // coalesced across tx (consecutive t)
        }
    }
}

// ---------------------------------------------------------------------------
extern "C" void kernel_launch(void* const* d_in, const int* in_sizes, int n_in,
                              void* d_out, int out_size, void* d_ws, size_t ws_size,
                              hipStream_t stream) {
    const float* emb   = (const float*)d_in[0];
    const float* W_in  = (const float*)d_in[1];
    const float* b_in  = (const float*)d_in[2];
    const float* W_out = (const float*)d_in[3];
    const float* b_out = (const float*)d_in[4];
    const float* embed = (const float*)d_in[5];
    float* acc = (float*)d_out;       // quantized sum; residual = emb - acc

    int*   idxbuf = (int*)d_ws;                      // MM ints
    float* en     = (float*)((char*)d_ws + (size_t)MM * 4);   // Q*K floats

    hipMemsetAsync(d_out, 0, (size_t)BB * DIMM * TT * sizeof(float), stream);
    enorm_kernel<<<QQ * KK, 64, 0, stream>>>(embed, en);

    for (int q = 0; q < QQ; q++) {
        fused_pa_kernel<<<MM / TILE, 256, 0, stream>>>(
            emb, acc, W_in + (size_t)q * DIMM * CDD, b_in + (size_t)q * CDD,
            embed + (size_t)q * KK * CDD, en + (size_t)q * KK, idxbuf);
        decode_kernel<<<dim3(MM / 64, DIMM / 64), 256, 0, stream>>>(
            idxbuf, embed + (size_t)q * KK * CDD, W_out + (size_t)q * CDD * DIMM,
            b_out + (size_t)q * DIMM, acc);
    }
}

// Round 3
// 1569.990 us; speedup vs baseline: 1.4723x; 1.2383x over previous
//
#include <hip/hip_runtime.h>
#include <hip/hip_bf16.h>
#include <math.h>

#define BB   8
#define DIMM 1024
#define TT   2048
#define CDD  128
#define KK   1024
#define QQ   8
#define MM   (BB*TT)   // 16384 tokens
#define TILE 32        // tokens per fused block
#define DK   64        // phase-1 d-chunk

typedef __attribute__((ext_vector_type(8))) short bf16x8;
typedef __attribute__((ext_vector_type(4))) float f32x4;

static __device__ inline unsigned short f2bf(float f) {
    __hip_bfloat16 h = __float2bfloat16(f);
    unsigned short u; __builtin_memcpy(&u, &h, 2); return u;
}
static __device__ inline float bf2f(unsigned short u) {
    __hip_bfloat16 h; __builtin_memcpy(&h, &u, 2); return __bfloat162float(h);
}

// ---------------------------------------------------------------------------
// ||E_k||^2 for all Q*K codebook rows. One wave per row.
__global__ __launch_bounds__(64) void enorm_kernel(const float* __restrict__ E,
                                                   float* __restrict__ en) {
    int row = blockIdx.x;
    int lane = threadIdx.x;
    const float* e = E + (size_t)row * CDD;
    float v0 = e[lane], v1 = e[lane + 64];
    float s = v0 * v0 + v1 * v1;
    #pragma unroll
    for (int off = 32; off > 0; off >>= 1) s += __shfl_down(s, off);
    if (lane == 0) en[row] = s;
}

// ---------------------------------------------------------------------------
// Transpose + 3-way bf16 split of W_in: [q][d][c] fp32 -> Wt{h,m,l}[q][c][d] ushort
__global__ __launch_bounds__(256) void prep_wt_kernel(
    const float* __restrict__ Wi,
    unsigned short* __restrict__ Wh, unsigned short* __restrict__ Wm,
    unsigned short* __restrict__ Wl)
{
    __shared__ float tile[32][33];
    const int q = blockIdx.z, d0 = blockIdx.x * 32, c0 = blockIdx.y * 32;
    const float* src = Wi + ((size_t)q * DIMM + d0) * CDD + c0;
    #pragma unroll
    for (int i = 0; i < 4; i++) {
        int j = i * 256 + threadIdx.x;
        int r = j >> 5, c = j & 31;
        tile[r][c] = src[(size_t)r * CDD + c];
    }
    __syncthreads();
    size_t obase = ((size_t)q * CDD + c0) * DIMM + d0;
    #pragma unroll
    for (int i = 0; i < 4; i++) {
        int j = i * 256 + threadIdx.x;
        int r = j >> 5, c = j & 31;          // r: c-row, c: d-col
        float v = tile[c][r];
        unsigned short u1 = f2bf(v);  float v1 = bf2f(u1);
        unsigned short u2 = f2bf(v - v1); float v2 = bf2f(u2);
        unsigned short u3 = f2bf(v - v1 - v2);
        size_t o = obase + (size_t)r * DIMM + c;
        Wh[o] = u1; Wm[o] = u2; Wl[o] = u3;
    }
}

// ---------------------------------------------------------------------------
// Fused MFMA: h = (emb-acc)^T·Wi + bi  (6-pass exact-grade), then
// dist argmin over codebook (3-pass bf16 + per-lane top-2 + exact fp32 rescore).
__global__ __launch_bounds__(256) void fused_pa_kernel(
    const float* __restrict__ emb, const float* __restrict__ acc,
    const unsigned short* __restrict__ Wth, const unsigned short* __restrict__ Wtm,
    const unsigned short* __restrict__ Wtl, const float* __restrict__ bi,
    const float* __restrict__ Ef, const float* __restrict__ en,
    int* __restrict__ outidx)
{
    __shared__ __align__(16) char smem[61440];
    // phase 1 overlays
    unsigned short* Rh  = (unsigned short*)smem;            // [32][64]
    unsigned short* Rm  = Rh + 32 * 64;
    unsigned short* Rl  = Rm + 32 * 64;                      // ends 12288
    unsigned short* Wsh = (unsigned short*)(smem + 12288);   // [128][64]
    unsigned short* Wsm = Wsh + 128 * 64;
    unsigned short* Wsl = Wsm + 128 * 64;                    // ends 61440
    // phase 2 overlays
    float*          Hs  = (float*)smem;                      // [32][128] swizzled fp32
    unsigned short* Eh  = (unsigned short*)(smem + 16384);   // [64][128]
    unsigned short* El  = Eh + 64 * 128;                     // ends 49152
    float*          candv = (float*)(smem + 16384);          // [32][128]
    int*            candi = (int*)(smem + 32768);            // [32][128]

    const int tid  = threadIdx.x;
    const int m0   = blockIdx.x * TILE;
    const int bb   = m0 / TT, t0 = m0 % TT;
    const float* eb = emb + (size_t)bb * DIMM * TT + t0;
    const float* ab = acc + (size_t)bb * DIMM * TT + t0;

    const int lane = tid & 63;
    const int w    = tid >> 6;     // wave id 0..3
    const int col  = lane & 15;
    const int quad = lane >> 4;

    // ---------------- phase 1: h via 6-pass MFMA ----------------
    f32x4 acc1[2][2];
    #pragma unroll
    for (int m = 0; m < 2; m++)
        #pragma unroll
        for (int n = 0; n < 2; n++) acc1[m][n] = (f32x4){0.f, 0.f, 0.f, 0.f};

    for (int d0 = 0; d0 < DIMM; d0 += DK) {
        // stage residual R = emb - acc, 3-way split, t-major swizzled
        #pragma unroll
        for (int i = 0; i < 2; i++) {
            int j = i * 256 + tid;
            int d = j >> 3, tg = (j & 7) << 2;
            const float4 ev = *(const float4*)(eb + (size_t)(d0 + d) * TT + tg);
            const float4 av = *(const float4*)(ab + (size_t)(d0 + d) * TT + tg);
            float rv[4] = {ev.x - av.x, ev.y - av.y, ev.z - av.z, ev.w - av.w};
            int g = d >> 3, kl = d & 7;
            #pragma unroll
            for (int u = 0; u < 4; u++) {
                int t = tg + u;
                int off = t * 64 + ((g ^ (t & 7)) << 3) + kl;
                float v = rv[u];
                unsigned short u1 = f2bf(v);      float v1 = bf2f(u1);
                unsigned short u2 = f2bf(v - v1); float v2 = bf2f(u2);
                unsigned short u3 = f2bf(v - v1 - v2);
                Rh[off] = u1; Rm[off] = u2; Rl[off] = u3;
            }
        }
        // stage W chunk (already transposed+split in ws): [c][d0..d0+63]
        #pragma unroll
        for (int i = 0; i < 4; i++) {
            int j = i * 256 + tid;
            int c = j >> 3, g = j & 7;
            size_t go = (size_t)c * DIMM + d0 + (g << 3);
            int off = c * 64 + ((g ^ (c & 7)) << 3);
            *(bf16x8*)(Wsh + off) = *(const bf16x8*)(Wth + go);
            *(bf16x8*)(Wsm + off) = *(const bf16x8*)(Wtm + go);
            *(bf16x8*)(Wsl + off) = *(const bf16x8*)(Wtl + go);
        }
        __syncthreads();

        #pragma unroll
        for (int ks = 0; ks < 2; ks++) {
            bf16x8 af[2][3], bfr[2][3];
            #pragma unroll
            for (int m = 0; m < 2; m++) {
                int t = m * 16 + col;
                int off = t * 64 + ((((ks << 2) + quad) ^ (t & 7)) << 3);
                af[m][0] = *(const bf16x8*)(Rh + off);
                af[m][1] = *(const bf16x8*)(Rm + off);
                af[m][2] = *(const bf16x8*)(Rl + off);
            }
            #pragma unroll
            for (int n = 0; n < 2; n++) {
                int c = ((w << 1) + n) * 16 + col;
                int off = c * 64 + ((((ks << 2) + quad) ^ (c & 7)) << 3);
                bfr[n][0] = *(const bf16x8*)(Wsh + off);
                bfr[n][1] = *(const bf16x8*)(Wsm + off);
                bfr[n][2] = *(const bf16x8*)(Wsl + off);
            }
            #pragma unroll
            for (int m = 0; m < 2; m++)
                #pragma unroll
                for (int n = 0; n < 2; n++) {
                    f32x4 a = acc1[m][n];
                    a = __builtin_amdgcn_mfma_f32_16x16x32_bf16(af[m][0], bfr[n][0], a, 0, 0, 0);
                    a = __builtin_amdgcn_mfma_f32_16x16x32_bf16(af[m][1], bfr[n][0], a, 0, 0, 0);
                    a = __builtin_amdgcn_mfma_f32_16x16x32_bf16(af[m][2], bfr[n][0], a, 0, 0, 0);
                    a = __builtin_amdgcn_mfma_f32_16x16x32_bf16(af[m][0], bfr[n][1], a, 0, 0, 0);
                    a = __builtin_amdgcn_mfma_f32_16x16x32_bf16(af[m][1], bfr[n][1], a, 0, 0, 0);
                    a = __builtin_amdgcn_mfma_f32_16x16x32_bf16(af[m][0], bfr[n][2], a, 0, 0, 0);
                    acc1[m][n] = a;
                }
        }
        __syncthreads();
    }

    // write h (+bias) into swizzled fp32 Hs
    #pragma unroll
    for (int m = 0; m < 2; m++)
        #pragma unroll
        for (int n = 0; n < 2; n++) {
            int c = ((w << 1) + n) * 16 + col;
            float bv = bi[c];
            #pragma unroll
            for (int r = 0; r < 4; r++) {
                int t = m * 16 + (quad << 2) + r;
                int off = t * 128 + ((((c >> 3) ^ (t & 7))) << 3) + (c & 7);
                Hs[off] = acc1[m][n][r] + bv;
            }
        }
    __syncthreads();

    // ---------------- phase 2: argmin via 3-pass MFMA ----------------
    // A-frags (h) held in registers for all chunks
    bf16x8 ah[2][4], al[2][4];
    #pragma unroll
    for (int m = 0; m < 2; m++) {
        int t = m * 16 + col;
        #pragma unroll
        for (int ks = 0; ks < 4; ks++) {
            int g2 = (((ks << 2) + quad) ^ (t & 7));
            const float* hp = Hs + t * 128 + (g2 << 3);
            float v[8];
            *(f32x4*)(v)     = *(const f32x4*)(hp);
            *(f32x4*)(v + 4) = *(const f32x4*)(hp + 4);
            short hs[8], ls[8];
            #pragma unroll
            for (int j2 = 0; j2 < 8; j2++) {
                unsigned short u1 = f2bf(v[j2]); float v1 = bf2f(u1);
                unsigned short u2 = f2bf(v[j2] - v1);
                hs[j2] = (short)u1; ls[j2] = (short)u2;
            }
            ah[m][ks] = (bf16x8){hs[0], hs[1], hs[2], hs[3], hs[4], hs[5], hs[6], hs[7]};
            al[m][ks] = (bf16x8){ls[0], ls[1], ls[2], ls[3], ls[4], ls[5], ls[6], ls[7]};
        }
    }

    float tv1[8], tv2[8]; int ti1[8], ti2[8];
    #pragma unroll
    for (int s = 0; s < 8; s++) { tv1[s] = INFINITY; tv2[s] = INFINITY; ti1[s] = 1 << 30; ti2[s] = 1 << 30; }

    const int lc = (w << 4) + col;   // local code row 0..63 within chunk

    for (int k0 = 0; k0 < KK; k0 += 64) {
        // stage E chunk, split hi/lo inline from fp32
        #pragma unroll
        for (int i = 0; i < 8; i++) {
            int j = i * 256 + tid;
            int lr = j >> 5, cg = (j & 31) << 2;
            const float4 evv = *(const float4*)(Ef + (size_t)(k0 + lr) * CDD + cg);
            float v4[4] = {evv.x, evv.y, evv.z, evv.w};
            unsigned short uh[4], ul[4];
            #pragma unroll
            for (int u = 0; u < 4; u++) {
                uh[u] = f2bf(v4[u]); float v1 = bf2f(uh[u]);
                ul[u] = f2bf(v4[u] - v1);
            }
            int off = lr * 128 + ((((cg >> 3) ^ (lr & 7))) << 3) + (cg & 7);
            uint2 ph, pl;
            ph.x = (unsigned)uh[0] | ((unsigned)uh[1] << 16);
            ph.y = (unsigned)uh[2] | ((unsigned)uh[3] << 16);
            pl.x = (unsigned)ul[0] | ((unsigned)ul[1] << 16);
            pl.y = (unsigned)ul[2] | ((unsigned)ul[3] << 16);
            *(uint2*)(Eh + off) = ph;
            *(uint2*)(El + off) = pl;
        }
        __syncthreads();

        bf16x8 bh[4], bl[4];
        #pragma unroll
        for (int ks = 0; ks < 4; ks++) {
            int off = lc * 128 + ((((ks << 2) + quad) ^ (lc & 7)) << 3);
            bh[ks] = *(const bf16x8*)(Eh + off);
            bl[ks] = *(const bf16x8*)(El + off);
        }
        f32x4 d2[2];
        #pragma unroll
        for (int m = 0; m < 2; m++) {
            f32x4 dd = (f32x4){0.f, 0.f, 0.f, 0.f};
            #pragma unroll
            for (int ks = 0; ks < 4; ks++) {
                dd = __builtin_amdgcn_mfma_f32_16x16x32_bf16(ah[m][ks], bh[ks], dd, 0, 0, 0);
                dd = __builtin_amdgcn_mfma_f32_16x16x32_bf16(al[m][ks], bh[ks], dd, 0, 0, 0);
                dd = __builtin_amdgcn_mfma_f32_16x16x32_bf16(ah[m][ks], bl[ks], dd, 0, 0, 0);
            }
            d2[m] = dd;
        }
        int kcode = k0 + lc;
        float env = en[kcode];
        #pragma unroll
        for (int m = 0; m < 2; m++)
            #pragma unroll
            for (int r = 0; r < 4; r++) {
                float dist = fmaf(-2.f, d2[m][r], env);
                int s = (m << 2) + r;
                if (dist < tv1[s]) { tv2[s] = tv1[s]; ti2[s] = ti1[s]; tv1[s] = dist; ti1[s] = kcode; }
                else if (dist < tv2[s]) { tv2[s] = dist; ti2[s] = kcode; }
            }
        __syncthreads();
    }

    // dump per-lane top-2 candidates
    #pragma unroll
    for (int m = 0; m < 2; m++)
        #pragma unroll
        for (int r = 0; r < 4; r++) {
            int t = m * 16 + (quad << 2) + r;
            int s = (m << 2) + r;
            int base = t * 128 + ((w << 4) + col) * 2;
            candv[base] = tv1[s];     candi[base] = ti1[s];
            candv[base + 1] = tv2[s]; candi[base + 1] = ti2[s];
        }
    __syncthreads();

    // top-4 scan + exact fp32 rescore (same formula as the all-fp32 kernel)
    if (tid < TILE) {
        int t = tid;
        float bv[4]; int bi4[4];
        #pragma unroll
        for (int p = 0; p < 4; p++) { bv[p] = INFINITY; bi4[p] = 1 << 30; }
        for (int j = 0; j < 128; j++) {
            float v = candv[t * 128 + j]; int ii = candi[t * 128 + j];
            if (v < bv[3] || (v == bv[3] && ii < bi4[3])) {
                bv[3] = v; bi4[3] = ii;
                #pragma unroll
                for (int p = 3; p > 0; p--) {
                    if (bv[p] < bv[p - 1] || (bv[p] == bv[p - 1] && bi4[p] < bi4[p - 1])) {
                        float tv = bv[p]; bv[p] = bv[p - 1]; bv[p - 1] = tv;
                        int tii = bi4[p]; bi4[p] = bi4[p - 1]; bi4[p - 1] = tii;
                    }
                }
            }
        }
        float best = INFINITY; int bidx = 1 << 30;
        #pragma unroll
        for (int p = 0; p < 4; p++) {
            int k = bi4[p]; if (k >= KK) continue;
            const float* er = Ef + (size_t)k * CDD;
            float dot = 0.f;
            for (int c = 0; c < CDD; c++) {
                float hv = Hs[t * 128 + (((c >> 3) ^ (t & 7)) << 3) + (c & 7)];
                dot = fmaf(hv, er[c], dot);
            }
            float dist = fmaf(-2.f, dot, en[k]);
            if (dist < best || (dist == best && k < bidx)) { best = dist; bidx = k; }
        }
        outidx[m0 + t] = bidx;
    }
}

// ---------------------------------------------------------------------------
// acc[b, d, t] += sum_c E[idx[m], c] * Wo[c, d] + bo[d]   (unchanged fp32)
__global__ __launch_bounds__(256) void decode_kernel(
    const int* __restrict__ idxp, const float* __restrict__ E,
    const float* __restrict__ Wo, const float* __restrict__ bo,
    float* __restrict__ acc)
{
    __shared__ float As[64][132];
    __shared__ float Bs[128][68];
    __shared__ int ids[64];
    const int tid = threadIdx.x;
    const int m0 = blockIdx.x * 64;
    const int d0 = blockIdx.y * 64;
    const int b = m0 / TT, t0 = m0 % TT;
    const int tx = tid & 15, ty = tid >> 4;

    if (tid < 64) ids[tid] = idxp[m0 + tid];
    __syncthreads();
    #pragma unroll
    for (int i = 0; i < 8; i++) {
        int j = i * 256 + tid;
        int row = j >> 5, c = (j & 31) << 2;
        *(float4*)&As[row][c] = *(const float4*)(E + (size_t)ids[row] * CDD + c);
    }
    #pragma unroll
    for (int i = 0; i < 8; i++) {
        int j = i * 256 + tid;
        int row = j >> 4, c = (j & 15) << 2;
        *(float4*)&Bs[row][c] = *(const float4*)(Wo + (size_t)row * DIMM + d0 + c);
    }
    __syncthreads();

    float dot[4][4];
    #pragma unroll
    for (int i = 0; i < 4; i++)
        #pragma unroll
        for (int j = 0; j < 4; j++) dot[i][j] = 0.f;

    #pragma unroll 4
    for (int c = 0; c < CDD; c += 4) {
        float4 av[4];
        #pragma unroll
        for (int i = 0; i < 4; i++) av[i] = *(float4*)&As[tx + (i << 4)][c];
        float4 b0 = *(float4*)&Bs[c + 0][ty << 2];
        float4 b1 = *(float4*)&Bs[c + 1][ty << 2];
        float4 b2 = *(float4*)&Bs[c + 2][ty << 2];
        float4 b3 = *(float4*)&Bs[c + 3][ty << 2];
        #pragma unroll
        for (int i = 0; i < 4; i++) {
            dot[i][0] = fmaf(av[i].x, b0.x, dot[i][0]);
            dot[i][1] = fmaf(av[i].x, b0.y, dot[i][1]);
            dot[i][2] = fmaf(av[i].x, b0.z, dot[i][2]);
            dot[i][3] = fmaf(av[i].x, b0.w, dot[i][3]);
            dot[i][0] = fmaf(av[i].y, b1.x, dot[i][0]);
            dot[i][1] = fmaf(av[i].y, b1.y, dot[i][1]);
            dot[i][2] = fmaf(av[i].y, b1.z, dot[i][2]);
            dot[i][3] = fmaf(av[i].y, b1.w, dot[i][3]);
            dot[i][0] = fmaf(av[i].z, b2.x, dot[i][0]);
            dot[i][1] = fmaf(av[i].z, b2.y, dot[i][1]);
            dot[i][2] = fmaf(av[i].z, b2.z, dot[i][2]);
            dot[i][3] = fmaf(av[i].z, b2.w, dot[i][3]);
            dot[i][0] = fmaf(av[i].w, b3.x, dot[i][0]);
            dot[i][1] = fmaf(av[i].w, b3.y, dot[i][1]);
            dot[i][2] = fmaf(av[i].w, b3.z, dot[i][2]);
            dot[i][3] = fmaf(av[i].w, b3.w, dot[i][3]);
        }
    }

    #pragma unroll
    for (int j = 0; j < 4; j++) {
        int d = d0 + (ty << 2) + j;
        float bj = bo[d];
        float* base = acc + (size_t)b * DIMM * TT + (size_t)d * TT + t0 + tx;
        #pragma unroll
        for (int i = 0; i < 4; i++) {
            base[i << 4] += dot[i][j] + bj;
        }
    }
}

// ---------------------------------------------------------------------------
extern "C" void kernel_launch(void* const* d_in, const int* in_sizes, int n_in,
                              void* d_out, int out_size, void* d_ws, size_t ws_size,
                              hipStream_t stream) {
    const float* emb   = (const float*)d_in[0];
    const float* W_in  = (const float*)d_in[1];
    const float* b_in  = (const float*)d_in[2];
    const float* W_out = (const float*)d_in[3];
    const float* b_out = (const float*)d_in[4];
    const float* embed = (const float*)d_in[5];
    float* acc = (float*)d_out;     // quantized sum; residual = emb - acc

    char* ws = (char*)d_ws;
    int*   idxbuf = (int*)ws;                              // MM ints      (64 KB)
    float* en     = (float*)(ws + 65536);                  // Q*K floats   (32 KB)
    unsigned short* Wth = (unsigned short*)(ws + 98304);   // 2 MB
    unsigned short* Wtm = Wth + (size_t)QQ * CDD * DIMM;   // 2 MB
    unsigned short* Wtl = Wtm + (size_t)QQ * CDD * DIMM;   // 2 MB

    hipMemsetAsync(d_out, 0, (size_t)BB * DIMM * TT * sizeof(float), stream);
    prep_wt_kernel<<<dim3(DIMM / 32, CDD / 32, QQ), 256, 0, stream>>>(W_in, Wth, Wtm, Wtl);
    enorm_kernel<<<QQ * KK, 64, 0, stream>>>(embed, en);

    for (int q = 0; q < QQ; q++) {
        fused_pa_kernel<<<MM / TILE, 256, 0, stream>>>(
            emb, acc,
            Wth + (size_t)q * CDD * DIMM, Wtm + (size_t)q * CDD * DIMM,
            Wtl + (size_t)q * CDD * DIMM, b_in + (size_t)q * CDD,
            embed + (size_t)q * KK * CDD, en + (size_t)q * KK, idxbuf);
        decode_kernel<<<dim3(MM / 64, DIMM / 64), 256, 0, stream>>>(
            idxbuf, embed + (size_t)q * KK * CDD, W_out + (size_t)q * CDD * DIMM,
            b_out + (size_t)q * DIMM, acc);
    }
}

// Round 5
// 926.606 us; speedup vs baseline: 2.4946x; 1.6943x over previous
//
#include <hip/hip_runtime.h>
#include <hip/hip_bf16.h>
#include <math.h>

#define BB   8
#define DIMM 1024
#define TT   2048
#define CDD  128
#define KK   1024
#define QQ   8
#define MM   (BB*TT)     // 16384 tokens
#define NPAIR 28         // q*(q-1)/2 pairs p<q

typedef __attribute__((ext_vector_type(8))) short bf16x8;
typedef __attribute__((ext_vector_type(4))) float f32x4;

static __device__ __forceinline__ unsigned short f2bf(float f) {
    __hip_bfloat16 h = __float2bfloat16(f);
    unsigned short u; __builtin_memcpy(&u, &h, 2); return u;
}
static __device__ __forceinline__ float bf2f(unsigned short u) {
    __hip_bfloat16 h; __builtin_memcpy(&h, &u, 2); return __bfloat162float(h);
}

// ===========================================================================
// prep: emb [b][d][t] fp32 -> embT 3-way split bf16 [m=b*T+t][d]
__global__ __launch_bounds__(256) void prep_embT(
    const float* __restrict__ emb,
    unsigned short* __restrict__ Th, unsigned short* __restrict__ Tm,
    unsigned short* __restrict__ Tl)
{
    __shared__ float tile[32][36];
    const int t0 = blockIdx.x * 32, d0 = blockIdx.y * 32, b = blockIdx.z;
    const int tid = threadIdx.x;
    {
        int r = tid >> 3, cg = (tid & 7) << 2;
        *(float4*)&tile[r][cg] =
            *(const float4*)(emb + ((size_t)b * DIMM + d0 + r) * TT + t0 + cg);
    }
    __syncthreads();
    {
        int tt = tid >> 3, dg = (tid & 7) << 2;
        unsigned short h4[4], m4[4], l4[4];
        #pragma unroll
        for (int u = 0; u < 4; u++) {
            float v = tile[dg + u][tt];
            h4[u] = f2bf(v);              float v1 = bf2f(h4[u]);
            m4[u] = f2bf(v - v1);         float v2 = bf2f(m4[u]);
            l4[u] = f2bf(v - v1 - v2);
        }
        size_t o = ((size_t)b * TT + t0 + tt) * DIMM + d0 + dg;
        *(ushort4*)(Th + o) = *(ushort4*)h4;
        *(ushort4*)(Tm + o) = *(ushort4*)m4;
        *(ushort4*)(Tl + o) = *(ushort4*)l4;
    }
}

// prep: Wi [q][d][c] -> WiT 3-way split [q][c][d]
__global__ __launch_bounds__(256) void prep_wiT(
    const float* __restrict__ Wi,
    unsigned short* __restrict__ Th, unsigned short* __restrict__ Tm,
    unsigned short* __restrict__ Tl)
{
    __shared__ float tile[32][36];
    const int d0 = blockIdx.x * 32, c0 = blockIdx.y * 32, q = blockIdx.z;
    const int tid = threadIdx.x;
    {
        int r = tid >> 3, cg = (tid & 7) << 2;   // r: d, cg: c
        *(float4*)&tile[r][cg] =
            *(const float4*)(Wi + ((size_t)q * DIMM + d0 + r) * CDD + c0 + cg);
    }
    __syncthreads();
    {
        int cc = tid >> 3, dg = (tid & 7) << 2;
        unsigned short h4[4], m4[4], l4[4];
        #pragma unroll
        for (int u = 0; u < 4; u++) {
            float v = tile[dg + u][cc];
            h4[u] = f2bf(v);              float v1 = bf2f(h4[u]);
            m4[u] = f2bf(v - v1);         float v2 = bf2f(m4[u]);
            l4[u] = f2bf(v - v1 - v2);
        }
        size_t o = ((size_t)q * CDD + c0 + cc) * DIMM + d0 + dg;
        *(ushort4*)(Th + o) = *(ushort4*)h4;
        *(ushort4*)(Tm + o) = *(ushort4*)m4;
        *(ushort4*)(Tl + o) = *(ushort4*)l4;
    }
}

// prep: Wo [q][c][d] -> WoT hi/lo [q][d][c]
__global__ __launch_bounds__(256) void prep_woT(
    const float* __restrict__ Wo,
    unsigned short* __restrict__ Th, unsigned short* __restrict__ Tl)
{
    __shared__ float tile[32][36];
    const int c0 = blockIdx.x * 32, d0 = blockIdx.y * 32, q = blockIdx.z;
    const int tid = threadIdx.x;
    {
        int r = tid >> 3, dg = (tid & 7) << 2;   // r: c, dg: d
        *(float4*)&tile[r][dg] =
            *(const float4*)(Wo + ((size_t)q * CDD + c0 + r) * DIMM + d0 + dg);
    }
    __syncthreads();
    {
        int dd = tid >> 3, cg = (tid & 7) << 2;
        unsigned short h4[4], l4[4];
        #pragma unroll
        for (int u = 0; u < 4; u++) {
            float v = tile[cg + u][dd];
            h4[u] = f2bf(v);
            l4[u] = f2bf(v - bf2f(h4[u]));
        }
        size_t o = ((size_t)q * DIMM + d0 + dd) * CDD + c0 + cg;
        *(ushort4*)(Th + o) = *(ushort4*)h4;
        *(ushort4*)(Tl + o) = *(ushort4*)l4;
    }
}

// prep: E fp32 -> Eh/El bf16 [qk][c] + ||E||^2
__global__ __launch_bounds__(64) void prep_esplit(
    const float* __restrict__ E,
    unsigned short* __restrict__ Eh, unsigned short* __restrict__ El,
    float* __restrict__ en)
{
    int row = blockIdx.x, lane = threadIdx.x;
    const float* e = E + (size_t)row * CDD;
    float v0 = e[lane * 2], v1 = e[lane * 2 + 1];
    unsigned short h2[2], l2[2];
    h2[0] = f2bf(v0); l2[0] = f2bf(v0 - bf2f(h2[0]));
    h2[1] = f2bf(v1); l2[1] = f2bf(v1 - bf2f(h2[1]));
    size_t o = (size_t)row * CDD + lane * 2;
    *(ushort2*)(Eh + o) = *(ushort2*)h2;
    *(ushort2*)(El + o) = *(ushort2*)l2;
    float s = v0 * v0 + v1 * v1;
    #pragma unroll
    for (int off = 32; off > 0; off >>= 1) s += __shfl_down(s, off);
    if (lane == 0) en[row] = s;
}

// prep: prefix sums of b_out: Pb[q][d] = sum_{p<q} bo[p][d], q=0..8
__global__ __launch_bounds__(256) void prep_pb(const float* __restrict__ bo,
                                               float* __restrict__ Pb)
{
    int d = blockIdx.x * 256 + threadIdx.x;
    float s = 0.f;
    Pb[d] = 0.f;
    for (int q = 0; q < QQ; q++) {
        s += bo[(size_t)q * DIMM + d];
        Pb[(size_t)(q + 1) * DIMM + d] = s;
    }
}

// prep: cvec[q][c] = sum_d Pb[q][d] * Wi[q][d][c]
__global__ __launch_bounds__(128) void prep_cvec(const float* __restrict__ Pb,
                                                 const float* __restrict__ Wi,
                                                 float* __restrict__ cvec)
{
    int q = blockIdx.x, c = threadIdx.x;
    float s = 0.f;
    for (int d = 0; d < DIMM; d++)
        s = fmaf(Pb[(size_t)q * DIMM + d], Wi[((size_t)q * DIMM + d) * CDD + c], s);
    cvec[(size_t)q * CDD + c] = s;
}

// ===========================================================================
// hemb[q][m][c] = sum_d emb[m,d]*Wi_q[d,c] + bi_q[c] via 6-pass 3-way split
// MFMA (products 11,21,31,12,22,13 — rel err ~2^-26). Block: 128 m-rows,
// full N=128, BK=32. Grid: (MM/128, 1, QQ).
__global__ __launch_bounds__(256) void k_hemb6(
    const unsigned short* __restrict__ A0, const unsigned short* __restrict__ A1,
    const unsigned short* __restrict__ A2,
    const unsigned short* __restrict__ B0g, const unsigned short* __restrict__ B1g,
    const unsigned short* __restrict__ B2g,
    const float* __restrict__ biAll, float* __restrict__ hembAll)
{
    const int q = blockIdx.z;
    const unsigned short* Bq0 = B0g + (size_t)q * CDD * DIMM;
    const unsigned short* Bq1 = B1g + (size_t)q * CDD * DIMM;
    const unsigned short* Bq2 = B2g + (size_t)q * CDD * DIMM;
    const float* bias = biAll + (size_t)q * CDD;
    float* C = hembAll + (size_t)q * MM * CDD;

    __shared__ unsigned short sA[3][128 * 40];
    __shared__ unsigned short sB[3][128 * 40];
    const int tid = threadIdx.x, lane = tid & 63, w = tid >> 6;
    const int wy = w >> 1, wx = w & 1;
    const int col = lane & 15, quad = lane >> 4;
    const int m0 = blockIdx.x * 128;

    f32x4 acc[4][4];
    #pragma unroll
    for (int i = 0; i < 4; i++)
        #pragma unroll
        for (int j = 0; j < 4; j++) acc[i][j] = (f32x4){0.f, 0.f, 0.f, 0.f};

    const int r = tid >> 1, s = (tid & 1) << 4;
    const int so = r * 40 + s;

    for (int k0 = 0; k0 < DIMM; k0 += 32) {
        {
            size_t ga = (size_t)(m0 + r) * DIMM + k0 + s;
            size_t gb = (size_t)r * DIMM + k0 + s;
            *(bf16x8*)(sA[0] + so)     = *(const bf16x8*)(A0 + ga);
            *(bf16x8*)(sA[0] + so + 8) = *(const bf16x8*)(A0 + ga + 8);
            *(bf16x8*)(sA[1] + so)     = *(const bf16x8*)(A1 + ga);
            *(bf16x8*)(sA[1] + so + 8) = *(const bf16x8*)(A1 + ga + 8);
            *(bf16x8*)(sA[2] + so)     = *(const bf16x8*)(A2 + ga);
            *(bf16x8*)(sA[2] + so + 8) = *(const bf16x8*)(A2 + ga + 8);
            *(bf16x8*)(sB[0] + so)     = *(const bf16x8*)(Bq0 + gb);
            *(bf16x8*)(sB[0] + so + 8) = *(const bf16x8*)(Bq0 + gb + 8);
            *(bf16x8*)(sB[1] + so)     = *(const bf16x8*)(Bq1 + gb);
            *(bf16x8*)(sB[1] + so + 8) = *(const bf16x8*)(Bq1 + gb + 8);
            *(bf16x8*)(sB[2] + so)     = *(const bf16x8*)(Bq2 + gb);
            *(bf16x8*)(sB[2] + so + 8) = *(const bf16x8*)(Bq2 + gb + 8);
        }
        __syncthreads();

        // hoist all B-frags (12 regs-of-4)
        bf16x8 b0[4], b1[4], b2[4];
        #pragma unroll
        for (int nt = 0; nt < 4; nt++) {
            int rr = wx * 64 + nt * 16 + col;
            int o = rr * 40 + quad * 8;
            b0[nt] = *(const bf16x8*)(sB[0] + o);
            b1[nt] = *(const bf16x8*)(sB[1] + o);
            b2[nt] = *(const bf16x8*)(sB[2] + o);
        }
        #pragma unroll
        for (int mt = 0; mt < 4; mt++) {
            int rr = wy * 64 + mt * 16 + col;
            int o = rr * 40 + quad * 8;
            bf16x8 a0 = *(const bf16x8*)(sA[0] + o);
            bf16x8 a1 = *(const bf16x8*)(sA[1] + o);
            bf16x8 a2 = *(const bf16x8*)(sA[2] + o);
            #pragma unroll
            for (int nt = 0; nt < 4; nt++) {
                f32x4 a = acc[mt][nt];
                a = __builtin_amdgcn_mfma_f32_16x16x32_bf16(a0, b0[nt], a, 0, 0, 0);
                a = __builtin_amdgcn_mfma_f32_16x16x32_bf16(a1, b0[nt], a, 0, 0, 0);
                a = __builtin_amdgcn_mfma_f32_16x16x32_bf16(a2, b0[nt], a, 0, 0, 0);
                a = __builtin_amdgcn_mfma_f32_16x16x32_bf16(a0, b1[nt], a, 0, 0, 0);
                a = __builtin_amdgcn_mfma_f32_16x16x32_bf16(a1, b1[nt], a, 0, 0, 0);
                a = __builtin_amdgcn_mfma_f32_16x16x32_bf16(a0, b2[nt], a, 0, 0, 0);
                acc[mt][nt] = a;
            }
        }
        __syncthreads();
    }
    #pragma unroll
    for (int nt = 0; nt < 4; nt++) {
        int n = wx * 64 + nt * 16 + col;
        float bv = bias[n];
        #pragma unroll
        for (int mt = 0; mt < 4; mt++) {
            #pragma unroll
            for (int rr = 0; rr < 4; rr++) {
                int m = m0 + wy * 64 + mt * 16 + quad * 4 + rr;
                C[(size_t)m * CDD + n] = acc[mt][nt][rr] + bv;
            }
        }
    }
}

// ===========================================================================
// 3-pass core (for D = E·Wo — output-only path, 2.6e-6 abs err, way below
// bf16-comparison threshold). A: [m][k] hi/lo, B: [n][k] hi/lo, 128×128 tile.
__device__ __forceinline__ void gemm3p_core(
    const unsigned short* __restrict__ Ah, const unsigned short* __restrict__ Al,
    const unsigned short* __restrict__ Bh, const unsigned short* __restrict__ Bl,
    float* __restrict__ C, int ldc, const float* __restrict__ bias,
    int K, int m0, int n0)
{
    __shared__ unsigned short sAh[128 * 72], sAl[128 * 72];
    __shared__ unsigned short sBh[128 * 72], sBl[128 * 72];
    const int tid = threadIdx.x, lane = tid & 63, w = tid >> 6;
    const int wy = w >> 1, wx = w & 1;
    const int col = lane & 15, quad = lane >> 4;

    f32x4 acc[4][4];
    #pragma unroll
    for (int i = 0; i < 4; i++)
        #pragma unroll
        for (int j = 0; j < 4; j++) acc[i][j] = (f32x4){0.f, 0.f, 0.f, 0.f};

    for (int k0 = 0; k0 < K; k0 += 64) {
        int r = tid >> 1, s = (tid & 1) * 32;
        {
            const unsigned short* ga = Ah + (size_t)(m0 + r) * K + k0 + s;
            const unsigned short* gl = Al + (size_t)(m0 + r) * K + k0 + s;
            const unsigned short* gb = Bh + (size_t)(n0 + r) * K + k0 + s;
            const unsigned short* gc = Bl + (size_t)(n0 + r) * K + k0 + s;
            int o = r * 72 + s;
            #pragma unroll
            for (int u = 0; u < 4; u++) {
                *(bf16x8*)(sAh + o + u * 8) = *(const bf16x8*)(ga + u * 8);
                *(bf16x8*)(sAl + o + u * 8) = *(const bf16x8*)(gl + u * 8);
                *(bf16x8*)(sBh + o + u * 8) = *(const bf16x8*)(gb + u * 8);
                *(bf16x8*)(sBl + o + u * 8) = *(const bf16x8*)(gc + u * 8);
            }
        }
        __syncthreads();
        #pragma unroll
        for (int ks = 0; ks < 2; ks++) {
            bf16x8 ah[4], al[4], bh[4], bl[4];
            int oo = ((ks << 2) + quad) << 3;
            #pragma unroll
            for (int mt = 0; mt < 4; mt++) {
                int rr = wy * 64 + mt * 16 + col;
                ah[mt] = *(const bf16x8*)(sAh + rr * 72 + oo);
                al[mt] = *(const bf16x8*)(sAl + rr * 72 + oo);
            }
            #pragma unroll
            for (int nt = 0; nt < 4; nt++) {
                int rr = wx * 64 + nt * 16 + col;
                bh[nt] = *(const bf16x8*)(sBh + rr * 72 + oo);
                bl[nt] = *(const bf16x8*)(sBl + rr * 72 + oo);
            }
            #pragma unroll
            for (int mt = 0; mt < 4; mt++)
                #pragma unroll
                for (int nt = 0; nt < 4; nt++) {
                    f32x4 a = acc[mt][nt];
                    a = __builtin_amdgcn_mfma_f32_16x16x32_bf16(ah[mt], bh[nt], a, 0, 0, 0);
                    a = __builtin_amdgcn_mfma_f32_16x16x32_bf16(al[mt], bh[nt], a, 0, 0, 0);
                    a = __builtin_amdgcn_mfma_f32_16x16x32_bf16(ah[mt], bl[nt], a, 0, 0, 0);
                    acc[mt][nt] = a;
                }
        }
        __syncthreads();
    }
    #pragma unroll
    for (int nt = 0; nt < 4; nt++) {
        int n = n0 + wx * 64 + nt * 16 + col;
        float bv = bias ? bias[n - n0] : 0.f;
        #pragma unroll
        for (int mt = 0; mt < 4; mt++) {
            #pragma unroll
            for (int rr = 0; rr < 4; rr++) {
                int m = m0 + wy * 64 + mt * 16 + quad * 4 + rr;
                C[(size_t)m * ldc + n] = acc[mt][nt][rr] + bv;
            }
        }
    }
}

__global__ __launch_bounds__(256) void k_D(
    const unsigned short* __restrict__ Eh, const unsigned short* __restrict__ El,
    const unsigned short* __restrict__ WoTh, const unsigned short* __restrict__ WoTl,
    float* __restrict__ D)
{
    int p = blockIdx.z;
    gemm3p_core(Eh + (size_t)p * KK * CDD, El + (size_t)p * KK * CDD,
                WoTh + (size_t)p * DIMM * CDD, WoTl + (size_t)p * DIMM * CDD,
                D + (size_t)p * KK * DIMM, DIMM, nullptr,
                CDD, blockIdx.x * 128, blockIdx.y * 128);
}

// ===========================================================================
// small fp32 GEMM (64×64 tile): C = A[M×K]·B[K×N]
__device__ __forceinline__ void f32gemm64(
    const float* __restrict__ A, int lda, const float* __restrict__ B, int ldb,
    float* __restrict__ C, int ldc, int K, int m0, int n0)
{
    __shared__ float As[32][68];
    __shared__ float Bs[32][68];
    const int tid = threadIdx.x, tx = tid & 15, ty = tid >> 4;
    float dot[4][4];
    #pragma unroll
    for (int i = 0; i < 4; i++)
        #pragma unroll
        for (int j = 0; j < 4; j++) dot[i][j] = 0.f;

    for (int k0 = 0; k0 < K; k0 += 32) {
        #pragma unroll
        for (int i = 0; i < 2; i++) {
            int j = i * 256 + tid;
            int r = j >> 3, kc = (j & 7) << 2;
            float4 a = *(const float4*)(A + (size_t)(m0 + r) * lda + k0 + kc);
            As[kc + 0][r] = a.x; As[kc + 1][r] = a.y;
            As[kc + 2][r] = a.z; As[kc + 3][r] = a.w;
        }
        #pragma unroll
        for (int i = 0; i < 2; i++) {
            int j = i * 256 + tid;
            int kr = j >> 4, nc = (j & 15) << 2;
            *(float4*)&Bs[kr][nc] = *(const float4*)(B + (size_t)(k0 + kr) * ldb + n0 + nc);
        }
        __syncthreads();
        #pragma unroll 4
        for (int kk = 0; kk < 32; kk++) {
            float4 a4 = *(float4*)&As[kk][ty << 2];
            float4 b4 = *(float4*)&Bs[kk][tx << 2];
            float av[4] = {a4.x, a4.y, a4.z, a4.w};
            float bv[4] = {b4.x, b4.y, b4.z, b4.w};
            #pragma unroll
            for (int i = 0; i < 4; i++)
                #pragma unroll
                for (int j = 0; j < 4; j++)
                    dot[i][j] = fmaf(av[i], bv[j], dot[i][j]);
        }
        __syncthreads();
    }
    #pragma unroll
    for (int i = 0; i < 4; i++)
        *(float4*)(C + (size_t)(m0 + (ty << 2) + i) * ldc + n0 + (tx << 2)) =
            *(float4*)&dot[i][0];
}

// G[pair] = Wo_p · Wi_q   (128×128, K=1024)
__global__ __launch_bounds__(256) void gemm_G(
    const float* __restrict__ Wo, const float* __restrict__ Wi, float* __restrict__ G)
{
    int z = blockIdx.z, p = z, q = 1;
    while (p >= q) { p -= q; q++; }
    f32gemm64(Wo + (size_t)p * CDD * DIMM, DIMM,
              Wi + (size_t)q * DIMM * CDD, CDD,
              G + (size_t)z * CDD * CDD, CDD, DIMM,
              blockIdx.y * 64, blockIdx.x * 64);
}

// F[pair] = E_p · G[pair]   (1024×128, K=128)
__global__ __launch_bounds__(256) void gemm_F(
    const float* __restrict__ E, const float* __restrict__ G, float* __restrict__ F)
{
    int z = blockIdx.z, p = z, q = 1;
    while (p >= q) { p -= q; q++; }
    f32gemm64(E + (size_t)p * KK * CDD, CDD,
              G + (size_t)z * CDD * CDD, CDD,
              F + (size_t)z * KK * CDD, CDD, CDD,
              blockIdx.y * 64, blockIdx.x * 64);
}

// ===========================================================================
__device__ __forceinline__ void top4_insert(float (&v)[4], int (&id)[4],
                                            float nv, int nid) {
    if (nv < v[3] || (nv == v[3] && nid < id[3])) {
        v[3] = nv; id[3] = nid;
        #pragma unroll
        for (int p = 3; p > 0; p--) {
            if (v[p] < v[p - 1] || (v[p] == v[p - 1] && id[p] < id[p - 1])) {
                float tv = v[p]; v[p] = v[p - 1]; v[p - 1] = tv;
                int ti = id[p]; id[p] = id[p - 1]; id[p - 1] = ti;
            } else break;
        }
    }
}

// Chain: h = hemb_q - cvec_q - sum_{p<q} F[p][idx_p], then argmin via 3-pass
// MFMA + top2/lane + exact fp32 rescore of merged top-4. 32 tokens/block.
__global__ __launch_bounds__(256) void chain_pa(
    const float* __restrict__ hemb_q, const float* __restrict__ Fq,
    const float* __restrict__ cvec_q, const int* __restrict__ idx_all, int q,
    const unsigned short* __restrict__ EhT_q, const unsigned short* __restrict__ ElT_q,
    const float* __restrict__ Ef_q, const float* __restrict__ en_q,
    int* __restrict__ idx_out)
{
    __shared__ __align__(16) char smem[51712];
    float* Hs = (float*)smem;                               // [32][132] fp32
    unsigned short* Esh = (unsigned short*)(smem + 16896);  // [64][136]
    unsigned short* Esl = Esh + 64 * 136;                   // [64][136]
    float* candv = (float*)(smem + 16896);                  // overlay after loop
    int*   candi = (int*)(smem + 16896 + 16384);

    const int tid = threadIdx.x;
    const int m0 = blockIdx.x * 32;
    const int lane = tid & 63, w = tid >> 6;
    const int col = lane & 15, quad = lane >> 4;

    // ---- gather h ----
    {
        int t = tid >> 3, cg = (tid & 7) << 4;
        float hv[16];
        const float* hp = hemb_q + (size_t)(m0 + t) * CDD + cg;
        #pragma unroll
        for (int u = 0; u < 4; u++) *(float4*)&hv[u * 4] = *(const float4*)(hp + u * 4);
        const float* cv = cvec_q + cg;
        #pragma unroll
        for (int u = 0; u < 16; u++) hv[u] -= cv[u];
        for (int p = 0; p < q; p++) {
            int k = idx_all[(size_t)p * MM + m0 + t];
            const float* fp = Fq + ((size_t)p * KK + k) * CDD + cg;
            #pragma unroll
            for (int u = 0; u < 4; u++) {
                float4 f4 = *(const float4*)(fp + u * 4);
                hv[u * 4 + 0] -= f4.x; hv[u * 4 + 1] -= f4.y;
                hv[u * 4 + 2] -= f4.z; hv[u * 4 + 3] -= f4.w;
            }
        }
        float* hd = Hs + t * 132 + cg;
        #pragma unroll
        for (int u = 0; u < 4; u++) *(float4*)(hd + u * 4) = *(float4*)&hv[u * 4];
    }
    __syncthreads();

    // ---- A-frags (h) hi/lo in regs ----
    bf16x8 ah[2][4], al[2][4];
    #pragma unroll
    for (int m = 0; m < 2; m++) {
        int t = m * 16 + col;
        #pragma unroll
        for (int ks = 0; ks < 4; ks++) {
            const float* hp = Hs + t * 132 + ks * 32 + quad * 8;
            float v[8];
            *(f32x4*)(v) = *(const f32x4*)(hp);
            *(f32x4*)(v + 4) = *(const f32x4*)(hp + 4);
            short hs[8], ls[8];
            #pragma unroll
            for (int u = 0; u < 8; u++) {
                unsigned short u1 = f2bf(v[u]);
                hs[u] = (short)u1;
                ls[u] = (short)f2bf(v[u] - bf2f(u1));
            }
            ah[m][ks] = (bf16x8){hs[0],hs[1],hs[2],hs[3],hs[4],hs[5],hs[6],hs[7]};
            al[m][ks] = (bf16x8){ls[0],ls[1],ls[2],ls[3],ls[4],ls[5],ls[6],ls[7]};
        }
    }

    float tv1[8], tv2[8]; int ti1[8], ti2[8];
    #pragma unroll
    for (int s = 0; s < 8; s++) { tv1[s] = INFINITY; tv2[s] = INFINITY;
                                  ti1[s] = 1 << 30; ti2[s] = 1 << 30; }
    const int lc = (w << 4) + col;   // this lane's code within 64-chunk

    for (int k0 = 0; k0 < KK; k0 += 64) {
        {
            int row = tid >> 2, seg = (tid & 3) << 5;
            const unsigned short* gh = EhT_q + (size_t)(k0 + row) * CDD + seg;
            const unsigned short* gl = ElT_q + (size_t)(k0 + row) * CDD + seg;
            int o = row * 136 + seg;
            *(bf16x8*)(Esh + o)     = *(const bf16x8*)(gh);
            *(bf16x8*)(Esh + o + 8) = *(const bf16x8*)(gh + 8);
            *(bf16x8*)(Esh + o +16) = *(const bf16x8*)(gh + 16);
            *(bf16x8*)(Esh + o +24) = *(const bf16x8*)(gh + 24);
            *(bf16x8*)(Esl + o)     = *(const bf16x8*)(gl);
            *(bf16x8*)(Esl + o + 8) = *(const bf16x8*)(gl + 8);
            *(bf16x8*)(Esl + o +16) = *(const bf16x8*)(gl + 16);
            *(bf16x8*)(Esl + o +24) = *(const bf16x8*)(gl + 24);
        }
        __syncthreads();

        bf16x8 bh[4], bl[4];
        #pragma unroll
        for (int ks = 0; ks < 4; ks++) {
            int o = lc * 136 + (((ks << 2) + quad) << 3);
            bh[ks] = *(const bf16x8*)(Esh + o);
            bl[ks] = *(const bf16x8*)(Esl + o);
        }
        f32x4 d2[2];
        #pragma unroll
        for (int m = 0; m < 2; m++) {
            f32x4 dd = (f32x4){0.f, 0.f, 0.f, 0.f};
            #pragma unroll
            for (int ks = 0; ks < 4; ks++) {
                dd = __builtin_amdgcn_mfma_f32_16x16x32_bf16(ah[m][ks], bh[ks], dd, 0, 0, 0);
                dd = __builtin_amdgcn_mfma_f32_16x16x32_bf16(al[m][ks], bh[ks], dd, 0, 0, 0);
                dd = __builtin_amdgcn_mfma_f32_16x16x32_bf16(ah[m][ks], bl[ks], dd, 0, 0, 0);
            }
            d2[m] = dd;
        }
        int kcode = k0 + lc;
        float env = en_q[kcode];
        #pragma unroll
        for (int m = 0; m < 2; m++)
            #pragma unroll
            for (int rr = 0; rr < 4; rr++) {
                float dist = fmaf(-2.f, d2[m][rr], env);
                int s = (m << 2) + rr;
                if (dist < tv1[s]) { tv2[s] = tv1[s]; ti2[s] = ti1[s];
                                     tv1[s] = dist;   ti1[s] = kcode; }
                else if (dist < tv2[s]) { tv2[s] = dist; ti2[s] = kcode; }
            }
        __syncthreads();
    }

    // ---- dump per-lane top2 ----
    #pragma unroll
    for (int m = 0; m < 2; m++)
        #pragma unroll
        for (int rr = 0; rr < 4; rr++) {
            int t = m * 16 + (quad << 2) + rr;
            int s = (m << 2) + rr;
            int base = t * 128 + lc * 2;
            candv[base] = tv1[s];     candi[base] = ti1[s];
            candv[base + 1] = tv2[s]; candi[base + 1] = ti2[s];
        }
    __syncthreads();

    // ---- merge to top-4 (8 threads per token) + exact fp32 rescore ----
    {
        int t = tid >> 3, j = tid & 7;
        float v[4]; int id[4];
        #pragma unroll
        for (int p = 0; p < 4; p++) { v[p] = INFINITY; id[p] = 1 << 30; }
        #pragma unroll
        for (int e = 0; e < 16; e++)
            top4_insert(v, id, candv[t * 128 + j * 16 + e], candi[t * 128 + j * 16 + e]);
        #pragma unroll
        for (int d = 1; d < 8; d <<= 1) {
            #pragma unroll
            for (int s = 0; s < 4; s++) {
                float pv = __shfl_xor(v[s], d);
                int   pi = __shfl_xor(id[s], d);
                top4_insert(v, id, pv, pi);
            }
        }
        // rescore: thread j handles candidate j&3, half j>>2
        int cand = id[j & 3];
        const float* er = Ef_q + (size_t)cand * CDD + ((j >> 2) << 6);
        const float* hr = Hs + t * 132 + ((j >> 2) << 6);
        float dot = 0.f;
        #pragma unroll 8
        for (int c = 0; c < 64; c++) dot = fmaf(hr[c], er[c], dot);
        dot += __shfl_xor(dot, 4);
        float dist = fmaf(-2.f, dot, en_q[cand]);
        #pragma unroll
        for (int d = 1; d < 4; d <<= 1) {
            float ov = __shfl_xor(dist, d);
            int   oi = __shfl_xor(cand, d);
            if (ov < dist || (ov == dist && oi < cand)) { dist = ov; cand = oi; }
        }
        if (j == 0) idx_out[m0 + t] = cand;
    }
}

// ===========================================================================
// out[b][d][t] = sum_p D_p[idx_p[m]][d] + Pb[8][d]
__global__ __launch_bounds__(256) void final_out(
    const int* __restrict__ idx_all, const float* __restrict__ D,
    const float* __restrict__ PbFull, float* __restrict__ out)
{
    __shared__ int ids[QQ][64];
    const int tid = threadIdx.x;
    const int m0 = blockIdx.x * 64, d0 = blockIdx.y * 64;
    const int b = m0 / TT, t0 = m0 % TT;
    const int tx = tid & 15, ty = tid >> 4;
    #pragma unroll
    for (int e = 0; e < 2; e++) {
        int j = e * 256 + tid;
        int p = j >> 6, tt = j & 63;
        ids[p][tt] = idx_all[(size_t)p * MM + m0 + tt];
    }
    __syncthreads();

    float s[4][4];
    #pragma unroll
    for (int j = 0; j < 4; j++) {
        float bs = PbFull[d0 + (ty << 2) + j];
        #pragma unroll
        for (int i = 0; i < 4; i++) s[i][j] = bs;
    }
    #pragma unroll
    for (int p = 0; p < QQ; p++) {
        #pragma unroll
        for (int i = 0; i < 4; i++) {
            int row = ids[p][tx + (i << 4)];
            float4 dv = *(const float4*)(D + ((size_t)p * KK + row) * DIMM + d0 + (ty << 2));
            s[i][0] += dv.x; s[i][1] += dv.y; s[i][2] += dv.z; s[i][3] += dv.w;
        }
    }
    #pragma unroll
    for (int j = 0; j < 4; j++) {
        float* base = out + (size_t)b * DIMM * TT + (size_t)(d0 + (ty << 2) + j) * TT + t0 + tx;
        #pragma unroll
        for (int i = 0; i < 4; i++) base[i << 4] = s[i][j];
    }
}

// ===========================================================================
extern "C" void kernel_launch(void* const* d_in, const int* in_sizes, int n_in,
                              void* d_out, int out_size, void* d_ws, size_t ws_size,
                              hipStream_t stream) {
    const float* emb   = (const float*)d_in[0];
    const float* W_in  = (const float*)d_in[1];
    const float* b_in  = (const float*)d_in[2];
    const float* W_out = (const float*)d_in[3];
    const float* b_out = (const float*)d_in[4];
    const float* embed = (const float*)d_in[5];
    float* out = (float*)d_out;

    char* ws = (char*)d_ws;
    size_t off = 0;
    auto alloc = [&](size_t bytes) { char* p = ws + off; off = (off + bytes + 255) & ~(size_t)255; return p; };
    int*   idxbuf = (int*)alloc((size_t)QQ * MM * 4);
    float* en     = (float*)alloc((size_t)QQ * KK * 4);
    unsigned short* EhT = (unsigned short*)alloc((size_t)QQ * KK * CDD * 2);
    unsigned short* ElT = (unsigned short*)alloc((size_t)QQ * KK * CDD * 2);
    unsigned short* WiTh = (unsigned short*)alloc((size_t)QQ * CDD * DIMM * 2);
    unsigned short* WiTm = (unsigned short*)alloc((size_t)QQ * CDD * DIMM * 2);
    unsigned short* WiTl = (unsigned short*)alloc((size_t)QQ * CDD * DIMM * 2);
    unsigned short* WoTh = (unsigned short*)alloc((size_t)QQ * DIMM * CDD * 2);
    unsigned short* WoTl = (unsigned short*)alloc((size_t)QQ * DIMM * CDD * 2);
    unsigned short* embTh = (unsigned short*)alloc((size_t)MM * DIMM * 2);
    unsigned short* embTm = (unsigned short*)alloc((size_t)MM * DIMM * 2);
    unsigned short* embTl = (unsigned short*)alloc((size_t)MM * DIMM * 2);
    float* hemb = (float*)alloc((size_t)QQ * MM * CDD * 4);
    float* G    = (float*)alloc((size_t)NPAIR * CDD * CDD * 4);
    float* F    = (float*)alloc((size_t)NPAIR * KK * CDD * 4);
    float* D    = (float*)alloc((size_t)QQ * KK * DIMM * 4);
    float* Pb   = (float*)alloc((size_t)(QQ + 1) * DIMM * 4);
    float* cvec = (float*)alloc((size_t)QQ * CDD * 4);

    // preps (parallel, off-chain)
    prep_embT<<<dim3(TT / 32, DIMM / 32, BB), 256, 0, stream>>>(emb, embTh, embTm, embTl);
    prep_wiT<<<dim3(DIMM / 32, CDD / 32, QQ), 256, 0, stream>>>(W_in, WiTh, WiTm, WiTl);
    prep_woT<<<dim3(CDD / 32, DIMM / 32, QQ), 256, 0, stream>>>(W_out, WoTh, WoTl);
    prep_esplit<<<QQ * KK, 64, 0, stream>>>(embed, EhT, ElT, en);
    prep_pb<<<DIMM / 256, 256, 0, stream>>>(b_out, Pb);
    prep_cvec<<<QQ, 128, 0, stream>>>(Pb, W_in, cvec);

    k_hemb6<<<dim3(MM / 128, 1, QQ), 256, 0, stream>>>(
        embTh, embTm, embTl, WiTh, WiTm, WiTl, b_in, hemb);
    gemm_G<<<dim3(2, 2, NPAIR), 256, 0, stream>>>(W_out, W_in, G);
    gemm_F<<<dim3(2, 16, NPAIR), 256, 0, stream>>>(embed, G, F);
    k_D<<<dim3(KK / 128, DIMM / 128, QQ), 256, 0, stream>>>(EhT, ElT, WoTh, WoTl, D);

    // sequential chain: only gather + argmin
    for (int q = 0; q < QQ; q++) {
        chain_pa<<<MM / 32, 256, 0, stream>>>(
            hemb + (size_t)q * MM * CDD,
            F + (size_t)(q * (q - 1) / 2) * KK * CDD,
            cvec + (size_t)q * CDD,
            idxbuf, q,
            EhT + (size_t)q * KK * CDD, ElT + (size_t)q * KK * CDD,
            embed + (size_t)q * KK * CDD, en + (size_t)q * KK,
            idxbuf + (size_t)q * MM);
    }
    final_out<<<dim3(MM / 64, DIMM / 64), 256, 0, stream>>>(idxbuf, D, Pb + (size_t)QQ * DIMM, out);
}